// Round 3
// baseline (448.310 us; speedup 1.0000x reference)
//
#include <hip/hip_runtime.h>
#include <hip/hip_bf16.h>

typedef __attribute__((ext_vector_type(4))) float f32x4;
typedef __attribute__((ext_vector_type(8))) short bf16x8;
typedef __attribute__((ext_vector_type(8))) unsigned short u16x8;

__device__ __forceinline__ unsigned short f2bf(float f) {
  unsigned int u = __builtin_bit_cast(unsigned int, f);
  unsigned int r = (u + 0x7FFFu + ((u >> 16) & 1u)) >> 16;
  return (unsigned short)r;
}
__device__ __forceinline__ float bf2f(unsigned short h) {
  unsigned int u = ((unsigned int)h) << 16;
  return __builtin_bit_cast(float, u);
}

__device__ __forceinline__ void gload_lds16(const void* g, void* l) {
  __builtin_amdgcn_global_load_lds(
      (__attribute__((address_space(1))) unsigned int*)g,
      (__attribute__((address_space(3))) unsigned int*)l, 16, 0, 0);
}

// ---------- fp32 -> bf16 bulk convert ----------
__global__ __launch_bounds__(256) void cvt_bf16(const float* __restrict__ in,
                                                unsigned short* __restrict__ out,
                                                long n) {
  long i = ((long)blockIdx.x * 256 + threadIdx.x) * 8;
  if (i >= n) return;
  f32x4 a = *(const f32x4*)(in + i);
  f32x4 b = *(const f32x4*)(in + i + 4);
  u16x8 o;
#pragma unroll
  for (int j = 0; j < 4; ++j) o[j] = f2bf(a[j]);
#pragma unroll
  for (int j = 0; j < 4; ++j) o[4 + j] = f2bf(b[j]);
  *(u16x8*)(out + i) = o;
}

// ---------- weight transpose + hi/lo split ----------
__global__ __launch_bounds__(256) void transpose_split(
    const float* __restrict__ W, unsigned short* __restrict__ Th,
    unsigned short* __restrict__ Tl, int K, int N) {
  __shared__ float tile[32][33];
  int n0 = blockIdx.x * 32, k0 = blockIdx.y * 32;
  int tx = threadIdx.x, ty = threadIdx.y;  // (32, 8)
#pragma unroll
  for (int r = 0; r < 4; ++r)
    tile[ty + 8 * r][tx] = W[(size_t)(k0 + ty + 8 * r) * N + n0 + tx];
  __syncthreads();
#pragma unroll
  for (int r = 0; r < 4; ++r) {
    float f = tile[tx][ty + 8 * r];
    unsigned short hi = f2bf(f);
    unsigned short lo = f2bf(f - bf2f(hi));
    size_t o = (size_t)(n0 + ty + 8 * r) * K + k0 + tx;
    Th[o] = hi;
    Tl[o] = lo;
  }
}

// ---------- bf16x2 GEMM ----------
// EPI: 0 = fp32 C; 2 = kv scatter (K-half -> kvT[bt][h][d][key], V-half -> kvV)
#define BM 128
#define BN 128
#define BK 64

template <int EPI>
__global__ __launch_bounds__(256) void gemm2(
    const unsigned short* __restrict__ A, const unsigned short* __restrict__ Bh,
    const unsigned short* __restrict__ Bl, void* __restrict__ Cv,
    void* __restrict__ Cv2, int M, int N, int K) {
  __shared__ unsigned short Ald[BM * BK];
  __shared__ unsigned short Bhld[BN * BK];
  __shared__ unsigned short Blld[BN * BK];
  int tid = threadIdx.x, lane = tid & 63, wid = tid >> 6;
  int wr = wid >> 1, wc = wid & 1;
  int nTN = N / BN;
  int bm = blockIdx.x / nTN, bn = blockIdx.x % nTN;
  const unsigned short* Ab = A + (size_t)(bm * BM) * K;
  const unsigned short* Bhb = Bh + (size_t)(bn * BN) * K;
  const unsigned short* Blb = Bl + (size_t)(bn * BN) * K;
  int fr = lane & 15, fq = lane >> 4;
  int srow = lane >> 3, scol = (lane & 7) * 8;

  f32x4 acc[4][4];
#pragma unroll
  for (int i = 0; i < 4; ++i)
#pragma unroll
    for (int j = 0; j < 4; ++j) acc[i][j] = (f32x4){0.f, 0.f, 0.f, 0.f};

  for (int k0 = 0; k0 < K; k0 += BK) {
#pragma unroll
    for (int i = 0; i < 4; ++i) {
      int c = wid * 4 + i;
      size_t go = (size_t)(c * 8 + srow) * K + k0 + scol;
      gload_lds16(Ab + go, &Ald[c * 512]);
      gload_lds16(Bhb + go, &Bhld[c * 512]);
      gload_lds16(Blb + go, &Blld[c * 512]);
    }
    __syncthreads();
#pragma unroll
    for (int kk = 0; kk < 2; ++kk) {
      bf16x8 af[4], bhf[4], blf[4];
#pragma unroll
      for (int i = 0; i < 4; ++i) {
        af[i] = *(const bf16x8*)&Ald[(wr * 64 + i * 16 + fr) * BK + kk * 32 + fq * 8];
        bhf[i] = *(const bf16x8*)&Bhld[(wc * 64 + i * 16 + fr) * BK + kk * 32 + fq * 8];
        blf[i] = *(const bf16x8*)&Blld[(wc * 64 + i * 16 + fr) * BK + kk * 32 + fq * 8];
      }
#pragma unroll
      for (int mi = 0; mi < 4; ++mi)
#pragma unroll
        for (int ni = 0; ni < 4; ++ni) {
          acc[mi][ni] = __builtin_amdgcn_mfma_f32_16x16x32_bf16(
              af[mi], bhf[ni], acc[mi][ni], 0, 0, 0);
          acc[mi][ni] = __builtin_amdgcn_mfma_f32_16x16x32_bf16(
              af[mi], blf[ni], acc[mi][ni], 0, 0, 0);
        }
    }
    __syncthreads();
  }

#pragma unroll
  for (int mi = 0; mi < 4; ++mi)
#pragma unroll
    for (int ni = 0; ni < 4; ++ni)
#pragma unroll
      for (int r = 0; r < 4; ++r) {
        int row = bm * BM + wr * 64 + mi * 16 + fq * 4 + r;
        int col = bn * BN + wc * 64 + ni * 16 + fr;
        if constexpr (EPI == 0) {
          ((float*)Cv)[(size_t)row * N + col] = acc[mi][ni][r];
        } else {  // EPI == 2: kv scatter
          if (col < 512) {
            int bt = row >> 6, key = row & 63, h = col >> 6, d = col & 63;
            ((float*)Cv)[(size_t)(bt * 8 + h) * 4096 + d * 64 + key] =
                acc[mi][ni][r];
          } else {
            ((float*)Cv2)[(size_t)row * 512 + (col - 512)] = acc[mi][ni][r];
          }
        }
      }
}

// ---------- gather rows by (b, t) ----------
__global__ __launch_bounds__(256) void gather_rows(const int* __restrict__ mask,
                                                   int* __restrict__ cnt,
                                                   int* __restrict__ idx) {
  int g = blockIdx.x * 256 + threadIdx.x;  // 0..8191
  int m = mask[g];
  if (m > 0) {
    int bt = (g >> 11) * 3 + m - 1;
    int p = atomicAdd(&cnt[bt], 1);
    idx[bt * 2048 + p] = g;
  }
}

// ---------- attention: register-resident K/V per (b,t) ----------
// q: [8192,512] fp32; kvT: [12][8][64d][64key] fp32; kvV: [768,512] fp32
// attn: [8192,512] bf16 (pre-zeroed)
#define ACHUNK 12
__global__ __launch_bounds__(512) void attn2(
    const float* __restrict__ q, const float* __restrict__ kvT,
    const float* __restrict__ kvV, const int* __restrict__ cnt,
    const int* __restrict__ idx, unsigned short* __restrict__ attn) {
  __shared__ float pls[8][64];
  int wid = threadIdx.x >> 6, lane = threadIdx.x & 63;
  int bt = blockIdx.x / ACHUNK, chunk = blockIdx.x % ACHUNK;
  int n = cnt[bt];
  int w = chunk * 8 + wid;  // 0..95
  if (w >= n) return;
  const int* list = idx + bt * 2048;

  float kr[64], vv[64];
#pragma unroll 1
  for (int h = 0; h < 8; ++h) {
    const float* kt = kvT + (size_t)(bt * 8 + h) * 4096 + lane;
#pragma unroll
    for (int d = 0; d < 64; ++d) kr[d] = kt[d * 64];
    const float* vb = kvV + (size_t)bt * 64 * 512 + h * 64 + lane;
#pragma unroll
    for (int j = 0; j < 64; ++j) vv[j] = vb[(size_t)j * 512];

    for (int j = w; j < n; j += 8 * ACHUNK) {
      int g = list[j];
      const float* qrow = q + (size_t)g * 512 + h * 64;
      float dot = 0.f;
#pragma unroll
      for (int c = 0; c < 16; ++c) {
        f32x4 q4 = *(const f32x4*)(qrow + c * 4);  // broadcast load
        dot += q4[0] * kr[c * 4] + q4[1] * kr[c * 4 + 1] +
               q4[2] * kr[c * 4 + 2] + q4[3] * kr[c * 4 + 3];
      }
      float mx = dot;
#pragma unroll
      for (int o = 32; o; o >>= 1) mx = fmaxf(mx, __shfl_xor(mx, o));
      float p = __expf(dot - mx);
      float sm = p;
#pragma unroll
      for (int o = 32; o; o >>= 1) sm += __shfl_xor(sm, o);
      p /= sm;
      pls[wid][lane] = p;
      float acc = 0.f;
#pragma unroll
      for (int c = 0; c < 16; ++c) {
        f32x4 p4 = *(const f32x4*)&pls[wid][c * 4];  // broadcast read
        acc += p4[0] * vv[c * 4] + p4[1] * vv[c * 4 + 1] +
               p4[2] * vv[c * 4 + 2] + p4[3] * vv[c * 4 + 3];
      }
      attn[(size_t)g * 512 + h * 64 + lane] = f2bf(acc);
    }
  }
}

// ---------- launch ----------
extern "C" void kernel_launch(void* const* d_in, const int* in_sizes, int n_in,
                              void* d_out, int out_size, void* d_ws,
                              size_t ws_size, hipStream_t stream) {
  const float* latent = (const float*)d_in[0];
  const float* y = (const float*)d_in[1];
  const int* mask = (const int*)d_in[2];
  const float* W_vk = (const float*)d_in[3];
  const float* W_q = (const float*)d_in[4];
  const float* W_out = (const float*)d_in[5];
  float* out = (float*)d_out;

  char* ws = (char*)d_ws;
  size_t off = 0;
  auto alloc = [&](size_t bytes) -> void* {
    void* p = ws + off;
    off = (off + bytes + 255) & ~(size_t)255;
    return p;
  };
  unsigned short* WqT_h = (unsigned short*)alloc((size_t)512 * 4096 * 2);
  unsigned short* WqT_l = (unsigned short*)alloc((size_t)512 * 4096 * 2);
  unsigned short* WvkT_h = (unsigned short*)alloc((size_t)1024 * 2048 * 2);
  unsigned short* WvkT_l = (unsigned short*)alloc((size_t)1024 * 2048 * 2);
  unsigned short* WoT_h = (unsigned short*)alloc((size_t)4096 * 512 * 2);
  unsigned short* WoT_l = (unsigned short*)alloc((size_t)4096 * 512 * 2);
  unsigned short* ybf = (unsigned short*)alloc((size_t)8192 * 4096 * 2);
  unsigned short* latbf = (unsigned short*)alloc((size_t)768 * 2048 * 2);
  float* qbuf = (float*)alloc((size_t)8192 * 512 * 4);
  float* kvT = (float*)alloc((size_t)12 * 8 * 64 * 64 * 4);
  float* kvV = (float*)alloc((size_t)768 * 512 * 4);
  unsigned short* attnbuf = (unsigned short*)alloc((size_t)8192 * 512 * 2);
  int* cnt = (int*)alloc(12 * 4);
  int* idx = (int*)alloc((size_t)12 * 2048 * 4);

  hipMemsetAsync(cnt, 0, 12 * 4, stream);
  hipMemsetAsync(attnbuf, 0, (size_t)8192 * 512 * 2, stream);

  cvt_bf16<<<16384, 256, 0, stream>>>(y, ybf, (long)8192 * 4096);
  cvt_bf16<<<768, 256, 0, stream>>>(latent, latbf, (long)768 * 2048);

  dim3 tb(32, 8);
  transpose_split<<<dim3(16, 128), tb, 0, stream>>>(W_q, WqT_h, WqT_l, 4096, 512);
  transpose_split<<<dim3(32, 64), tb, 0, stream>>>(W_vk, WvkT_h, WvkT_l, 2048, 1024);
  transpose_split<<<dim3(128, 16), tb, 0, stream>>>(W_out, WoT_h, WoT_l, 512, 4096);

  gather_rows<<<32, 256, 0, stream>>>(mask, cnt, idx);

  // kv = latent[768,2048] @ W_vk ; scatter K -> kvT, V -> kvV
  gemm2<2><<<(768 / BM) * (1024 / BN), 256, 0, stream>>>(
      latbf, WvkT_h, WvkT_l, kvT, kvV, 768, 1024, 2048);
  // q = y[8192,4096] @ W_q -> fp32
  gemm2<0><<<(8192 / BM) * (512 / BN), 256, 0, stream>>>(
      ybf, WqT_h, WqT_l, qbuf, nullptr, 8192, 512, 4096);
  // attention
  attn2<<<12 * ACHUNK, 512, 0, stream>>>(qbuf, kvT, kvV, cnt, idx, attnbuf);
  // out = attn[8192,512] @ W_out -> fp32
  gemm2<0><<<(8192 / BM) * (4096 / BN), 256, 0, stream>>>(
      attnbuf, WoT_h, WoT_l, out, nullptr, 8192, 4096, 512);
}